// Round 22
// baseline (114.247 us; speedup 1.0000x reference)
//
#include <hip/hip_runtime.h>

#define TSEQ 512
#define CDIM 512
#define NH 8
#define HS 64
#define BBATCH 32
#define MROWS (BBATCH * TSEQ)   // 16384

typedef unsigned short u16;
typedef __bf16 bf16x8 __attribute__((ext_vector_type(8)));
typedef float f32x4 __attribute__((ext_vector_type(4)));
typedef float f32x16 __attribute__((ext_vector_type(16)));

// round-to-nearest-even fp32 -> bf16 bits
__device__ __forceinline__ u16 f2b(float f) {
  union { float f; unsigned u; } v; v.f = f;
  unsigned r = (v.u + 0x7fffu + ((v.u >> 16) & 1u)) >> 16;
  return (u16)r;
}

__device__ __forceinline__ void gload_lds16(const u16* g, u16* l) {
  __builtin_amdgcn_global_load_lds(
      (const __attribute__((address_space(1))) void*)g,
      (__attribute__((address_space(3))) void*)l, 16, 0, 0);
}

// ---------------- prep kernels ----------------
// k-blocked layout: 16B "units"; unit (kb, dim)[j] = M[kb*8+j][dim].

// x fp32 [16384][512] -> A2 units [64 kb][16384 m].  grid (128, 4)
__global__ __launch_bounds__(256) void conv_x(const float* __restrict__ x,
                                              u16* __restrict__ A2) {
  __shared__ __align__(16) u16 tile[128][136];
  const int tid = threadIdx.x;
  const int m0 = blockIdx.x * 128;
  const int cc = blockIdx.y;
#pragma unroll
  for (int i = 0; i < 16; ++i) {
    int idx = i * 256 + tid;
    int ml = idx >> 5, c4 = idx & 31;
    float4 v = *reinterpret_cast<const float4*>(
        x + (size_t)(m0 + ml) * CDIM + cc * 128 + c4 * 4);
    ushort4 o; o.x = f2b(v.x); o.y = f2b(v.y); o.z = f2b(v.z); o.w = f2b(v.w);
    *reinterpret_cast<ushort4*>(&tile[ml][c4 * 4]) = o;
  }
  __syncthreads();
#pragma unroll
  for (int i = 0; i < 8; ++i) {
    int uid = i * 256 + tid;
    int kb = uid >> 7, ml = uid & 127;
    int4 v = *reinterpret_cast<const int4*>(&tile[ml][kb * 8]);
    *reinterpret_cast<int4*>(A2 + ((size_t)(cc * 16 + kb) * MROWS + m0 + ml) * 8) = v;
  }
}

// W fp32 [512 K][512 N] (natural) -> B2 units [64 kb][512 n] per matrix
__global__ __launch_bounds__(256) void transpose_w(const float* __restrict__ wq,
                                                   const float* __restrict__ wk,
                                                   const float* __restrict__ wv,
                                                   const float* __restrict__ wo,
                                                   u16* __restrict__ B2,
                                                   u16* __restrict__ B2o) {
  __shared__ __align__(16) u16 tile[64][136];
  const int tid = threadIdx.x;
  int mat = blockIdx.z;
  const float* src = (mat == 0) ? wq : (mat == 1) ? wk : (mat == 2) ? wv : wo;
  u16* dst = (mat < 3) ? (B2 + (size_t)mat * 64 * 512 * 8) : B2o;
  const int k0 = blockIdx.x * 64, n0 = blockIdx.y * 128;
#pragma unroll
  for (int i = 0; i < 8; ++i) {
    int idx = i * 256 + tid;
    int kl = idx >> 5, c4 = idx & 31;
    float4 v = *reinterpret_cast<const float4*>(
        src + (size_t)(k0 + kl) * CDIM + n0 + c4 * 4);
    ushort4 o; o.x = f2b(v.x); o.y = f2b(v.y); o.z = f2b(v.z); o.w = f2b(v.w);
    *reinterpret_cast<ushort4*>(&tile[kl][c4 * 4]) = o;
  }
  __syncthreads();
#pragma unroll
  for (int i = 0; i < 4; ++i) {
    int uid = i * 256 + tid;
    int kb = uid >> 7, nl = uid & 127;
    ushort4 lo, hi;
    lo.x = tile[kb * 8 + 0][nl]; lo.y = tile[kb * 8 + 1][nl];
    lo.z = tile[kb * 8 + 2][nl]; lo.w = tile[kb * 8 + 3][nl];
    hi.x = tile[kb * 8 + 4][nl]; hi.y = tile[kb * 8 + 5][nl];
    hi.z = tile[kb * 8 + 6][nl]; hi.w = tile[kb * 8 + 7][nl];
    u16* d = dst + ((size_t)(k0 / 8 + kb) * 512 + n0 + nl) * 8;
    *reinterpret_cast<ushort4*>(d) = lo;
    *reinterpret_cast<ushort4*>(d + 4) = hi;
  }
}

__global__ __launch_bounds__(256) void rope_tab(float* __restrict__ cosT,
                                                float* __restrict__ sinT) {
  int i = blockIdx.x * 256 + threadIdx.x;       // 512*32
  int t = i >> 5, f = i & 31;
  float inv = __powf(10000.0f, -(float)f / 32.0f);
  float ang = (float)t * inv;
  cosT[i] = cosf(ang);
  sinT[i] = sinf(ang);
}

// ------ fused QKV GEMM + RoPE: 256^2 tile, 8 waves, phase-split K-loop -----
// BK=32 (2 k-slices/tile); one barrier per K-tile; 2 blocks/CU, grid 384
// all co-resident. Epilogue: Q natural (pre-scaled), K/V fragment-packed.
__global__ __launch_bounds__(512, 2) void qkv_gemm(const u16* __restrict__ A2,
                                                   const u16* __restrict__ B2,
                                                   const float* __restrict__ cosT,
                                                   const float* __restrict__ sinT,
                                                   u16* __restrict__ Qb,
                                                   u16* __restrict__ Kf,
                                                   u16* __restrict__ Vf) {
  __shared__ __align__(16) u16 lds[2][16384];   // 2 x 32KB: A[4kb][256m] + B
  const int tid = threadIdx.x;
  const int lane = tid & 63;
  const int l31 = lane & 31, hh = lane >> 5;
  const int wid = tid >> 6;                      // 0..7
  const int wm = wid >> 2, wn = wid & 3;         // 2M x 4N waves
  const int m0 = blockIdx.x * 256;
  const int n0 = blockIdx.y * 256;
  const int mat = n0 >> 9;                       // 0:Q 1:K 2:V (256|512)
  const int nc0 = n0 & 511;
  const u16* B2m = B2 + (size_t)mat * (64 * 512 * 8);
  const int wmb = wm * 128, wnb = wn * 64;

  f32x16 acc[4][2] = {};

  auto stage = [&](int buf, int t) {             // 4 gload_lds per thread
#pragma unroll
    for (int c = 0; c < 2; ++c) {
      int u = c * 512 + tid;
      int kb = u >> 8, ml = u & 255;
      gload_lds16(A2 + ((size_t)(t * 4 + kb) * MROWS + m0 + ml) * 8,
                  &lds[buf][u * 8]);
    }
#pragma unroll
    for (int c = 0; c < 2; ++c) {
      int u = c * 512 + tid;
      int kb = u >> 8, nl = u & 255;
      gload_lds16(B2m + ((size_t)(t * 4 + kb) * 512 + nc0 + nl) * 8,
                  &lds[buf][8192 + u * 8]);
    }
  };

  stage(0, 0);
  asm volatile("s_waitcnt vmcnt(0)" ::: "memory");
  __builtin_amdgcn_sched_barrier(0);
  __builtin_amdgcn_s_barrier();
  __builtin_amdgcn_sched_barrier(0);
#pragma unroll
  for (int t = 0; t < 16; ++t) {
    const int cur = t & 1;
    const u16* LA = &lds[cur][0];
    const u16* LB = &lds[cur][8192];
#pragma unroll
    for (int p = 0; p < 2; ++p) {
      const int kb2 = p * 2 + hh;
      bf16x8 a0 = *reinterpret_cast<const bf16x8*>(LA + (kb2 * 256 + wmb + l31) * 8);
      bf16x8 a1 = *reinterpret_cast<const bf16x8*>(LA + (kb2 * 256 + wmb + 32 + l31) * 8);
      bf16x8 a2 = *reinterpret_cast<const bf16x8*>(LA + (kb2 * 256 + wmb + 64 + l31) * 8);
      bf16x8 a3 = *reinterpret_cast<const bf16x8*>(LA + (kb2 * 256 + wmb + 96 + l31) * 8);
      bf16x8 b0 = *reinterpret_cast<const bf16x8*>(LB + (kb2 * 256 + wnb + l31) * 8);
      bf16x8 b1 = *reinterpret_cast<const bf16x8*>(LB + (kb2 * 256 + wnb + 32 + l31) * 8);
      if (p == 0 && t + 1 < 16) stage(cur ^ 1, t + 1);  // all staging in phase 0
      asm volatile("s_waitcnt lgkmcnt(0)" ::: "memory");
      __builtin_amdgcn_sched_barrier(0);
      __builtin_amdgcn_s_setprio(1);
      acc[0][0] = __builtin_amdgcn_mfma_f32_32x32x16_bf16(a0, b0, acc[0][0], 0, 0, 0);
      acc[0][1] = __builtin_amdgcn_mfma_f32_32x32x16_bf16(a0, b1, acc[0][1], 0, 0, 0);
      acc[1][0] = __builtin_amdgcn_mfma_f32_32x32x16_bf16(a1, b0, acc[1][0], 0, 0, 0);
      acc[1][1] = __builtin_amdgcn_mfma_f32_32x32x16_bf16(a1, b1, acc[1][1], 0, 0, 0);
      acc[2][0] = __builtin_amdgcn_mfma_f32_32x32x16_bf16(a2, b0, acc[2][0], 0, 0, 0);
      acc[2][1] = __builtin_amdgcn_mfma_f32_32x32x16_bf16(a2, b1, acc[2][1], 0, 0, 0);
      acc[3][0] = __builtin_amdgcn_mfma_f32_32x32x16_bf16(a3, b0, acc[3][0], 0, 0, 0);
      acc[3][1] = __builtin_amdgcn_mfma_f32_32x32x16_bf16(a3, b1, acc[3][1], 0, 0, 0);
      __builtin_amdgcn_s_setprio(0);
    }
    // end of K-tile: next-tile loads landed + all waves done reading cur
    __builtin_amdgcn_sched_barrier(0);
    asm volatile("s_waitcnt vmcnt(0)" ::: "memory");
    __builtin_amdgcn_s_barrier();
    __builtin_amdgcn_sched_barrier(0);
  }

  const int bidx = m0 >> 9;
  if (mat == 0) {
    const float qs = 0.125f * 1.4426950408889634f;
#pragma unroll
    for (int nr = 0; nr < 2; ++nr) {
      int nc = nc0 + wnb + nr * 32 + l31;
      int fi = (nc & 63) >> 1;
      int odd = nc & 1;
#pragma unroll
      for (int mr = 0; mr < 4; ++mr)
#pragma unroll
        for (int r = 0; r < 16; ++r) {
          int row = m0 + wmb + mr * 32 + (r & 3) + 8 * (r >> 2) + 4 * hh;
          int tq = row & (TSEQ - 1);
          float v = acc[mr][nr][r];
          float o = __shfl_xor(v, 1);
          float c = cosT[tq * 32 + fi], sn = sinT[tq * 32 + fi];
          float res = odd ? (v * c + o * sn) : (v * c - o * sn);
          Qb[(size_t)row * CDIM + nc] = f2b(res * qs);
        }
    }
  } else if (mat == 1) {
    // K -> fragment-packed (round-20 verified map)
#pragma unroll
    for (int nr = 0; nr < 2; ++nr) {
      int nc = nc0 + wnb + nr * 32 + l31;
      int h2 = nc >> 6, e = nc & 63;
      int fi = e >> 1;
      int odd = nc & 1;
      int laneHi = ((e >> 3) & 1) * 32;
      int idx = ((e >> 4) * 8) + (e & 7);
#pragma unroll
      for (int mr = 0; mr < 4; ++mr)
#pragma unroll
        for (int r = 0; r < 16; ++r) {
          int row = m0 + wmb + mr * 32 + (r & 3) + 8 * (r >> 2) + 4 * hh;
          int tq = row & (TSEQ - 1);
          float v = acc[mr][nr][r];
          float o = __shfl_xor(v, 1);
          float c = cosT[tq * 32 + fi], sn = sinT[tq * 32 + fi];
          float res = odd ? (v * c + o * sn) : (v * c - o * sn);
          size_t addr = ((((size_t)(bidx * 8 + h2) * 16 + (tq >> 5)) * 64)
                         + laneHi + (tq & 31)) * 32 + idx;
          Kf[addr] = f2b(res);
        }
    }
  } else {
    // V -> fragment-packed (round-21 verified map)
#pragma unroll
    for (int nr = 0; nr < 2; ++nr) {
      int nc = nc0 + wnb + nr * 32 + l31;
      int h2 = nc >> 6, e = nc & 63;
      int e31 = e & 31, eHi = e >> 5;
#pragma unroll
      for (int mr = 0; mr < 4; ++mr)
#pragma unroll
        for (int r = 0; r < 16; ++r) {
          int row = m0 + wmb + mr * 32 + (r & 3) + 8 * (r >> 2) + 4 * hh;
          int tq = row & (TSEQ - 1);
          int t5 = tq & 31;
          size_t addr = ((((size_t)(bidx * 8 + h2) * 16 + (tq >> 5)) * 64)
                         + ((t5 >> 3) & 1) * 32 + e31) * 32
                        + (eHi * 2 + ((t5 >> 4) & 1)) * 8 + (t5 & 7);
          Vf[addr] = f2b(acc[mr][nr][r]);
        }
    }
  }
}

// -------- flash attention (frag-packed K/V + fixed-base softmax) ----------
__global__ __launch_bounds__(128, 4) void attn_kern(const u16* __restrict__ Qb,
                                                    const u16* __restrict__ Kf,
                                                    const u16* __restrict__ Vf,
                                                    u16* __restrict__ A2out) {
  const int lane = threadIdx.x & 63, wid = threadIdx.x >> 6;
  const int l31 = lane & 31, hh = lane >> 5;
  const int bh = blockIdx.x, b = bh >> 3, h = bh & 7;
  const int q0 = blockIdx.y * 64 + wid * 32;

  bf16x8 qf[4];
  const u16* qbase = Qb + (size_t)(b * TSEQ + q0 + l31) * CDIM + h * HS + hh * 8;
#pragma unroll
  for (int ds = 0; ds < 4; ++ds)
    qf[ds] = *reinterpret_cast<const bf16x8*>(qbase + ds * 16);

  float lsum = 0.0f;
  f32x16 of[2] = {};

  const int nkt = (q0 >> 5) + 1;
  for (int kt = 0; kt < nkt; ++kt) {
    const u16* kfr = Kf + (((size_t)bh * 16 + kt) * 64 + lane) * 32;
    f32x16 s = {};
    __builtin_amdgcn_s_setprio(1);
#pragma unroll
    for (int ds = 0; ds < 4; ++ds) {
      bf16x8 kf = *reinterpret_cast<const bf16x8*>(kfr + ds * 8);
      s = __builtin_amdgcn_mfma_f32_32x32x16_bf16(kf, qf[ds], s, 0, 0, 0);
    }
    __builtin_amdgcn_s_setprio(0);
    float p[16];
    if (kt == nkt - 1) {          // diagonal tile: zero k > q after exp
#pragma unroll
      for (int r = 0; r < 16; ++r) {
        int kk = (r & 3) + 8 * (r >> 2) + 4 * hh;
        p[r] = (kk > l31) ? 0.0f : exp2f(s[r]);
      }
    } else {
#pragma unroll
      for (int r = 0; r < 16; ++r) p[r] = exp2f(s[r]);
    }
    float ts = 0.0f;
#pragma unroll
    for (int r = 0; r < 16; ++r) ts += p[r];
    ts += __shfl_xor(ts, 32);
    lsum += ts;

    unsigned w0, w1, w2, w3, w4, w5, w6, w7;
    asm("v_cvt_pk_bf16_f32 %0, %1, %2" : "=v"(w0) : "v"(p[0]),  "v"(p[1]));
    asm("v_cvt_pk_bf16_f32 %0, %1, %2" : "=v"(w1) : "v"(p[2]),  "v"(p[3]));
    asm("v_cvt_pk_bf16_f32 %0, %1, %2" : "=v"(w2) : "v"(p[4]),  "v"(p[5]));
    asm("v_cvt_pk_bf16_f32 %0, %1, %2" : "=v"(w3) : "v"(p[6]),  "v"(p[7]));
    asm("v_cvt_pk_bf16_f32 %0, %1, %2" : "=v"(w4) : "v"(p[8]),  "v"(p[9]));
    asm("v_cvt_pk_bf16_f32 %0, %1, %2" : "=v"(w5) : "v"(p[10]), "v"(p[11]));
    asm("v_cvt_pk_bf16_f32 %0, %1, %2" : "=v"(w6) : "v"(p[12]), "v"(p[13]));
    asm("v_cvt_pk_bf16_f32 %0, %1, %2" : "=v"(w7) : "v"(p[14]), "v"(p[15]));
    asm("v_permlane32_swap_b32 %0, %1" : "+v"(w0), "+v"(w2));
    asm("v_permlane32_swap_b32 %0, %1" : "+v"(w1), "+v"(w3));
    asm("v_permlane32_swap_b32 %0, %1" : "+v"(w4), "+v"(w6));
    asm("v_permlane32_swap_b32 %0, %1" : "+v"(w5), "+v"(w7));
    union { unsigned u[4]; bf16x8 v; } pb0, pb1;
    pb0.u[0] = w0; pb0.u[1] = w1; pb0.u[2] = w2; pb0.u[3] = w3;
    pb1.u[0] = w4; pb1.u[1] = w5; pb1.u[2] = w6; pb1.u[3] = w7;

    const u16* vfr = Vf + (((size_t)bh * 16 + kt) * 64 + lane) * 32;
    bf16x8 vf00 = *reinterpret_cast<const bf16x8*>(vfr);
    bf16x8 vf01 = *reinterpret_cast<const bf16x8*>(vfr + 8);
    bf16x8 vf10 = *reinterpret_cast<const bf16x8*>(vfr + 16);
    bf16x8 vf11 = *reinterpret_cast<const bf16x8*>(vfr + 24);
    __builtin_amdgcn_s_setprio(1);
    of[0] = __builtin_amdgcn_mfma_f32_32x32x16_bf16(vf00, pb0.v, of[0], 0, 0, 0);
    of[0] = __builtin_amdgcn_mfma_f32_32x32x16_bf16(vf01, pb1.v, of[0], 0, 0, 0);
    of[1] = __builtin_amdgcn_mfma_f32_32x32x16_bf16(vf10, pb0.v, of[1], 0, 0, 0);
    of[1] = __builtin_amdgcn_mfma_f32_32x32x16_bf16(vf11, pb1.v, of[1], 0, 0, 0);
    __builtin_amdgcn_s_setprio(0);
  }

  // ---- write O directly in k-blocked A2 units ----
  float inv = 1.0f / lsum;
  const int grow = b * TSEQ + q0 + l31;
#pragma unroll
  for (int dt = 0; dt < 2; ++dt)
#pragma unroll
    for (int i = 0; i < 8; ++i) {
      ushort2 st;
      st.x = f2b(of[dt][2 * i] * inv);
      st.y = f2b(of[dt][2 * i + 1] * inv);
      int kb = h * 8 + dt * 4 + ((2 * i) >> 2);
      int off = ((2 * i) & 3) + 4 * hh;
      *reinterpret_cast<ushort2*>(
          A2out + ((size_t)kb * MROWS + grow) * 8 + off) = st;
    }
}

// ------- output projection (32x32 MFMA, BK=32, 3-buf counted vmcnt) --------
__global__ __launch_bounds__(256, 2) void out_gemm(const u16* __restrict__ A2,
                                                   const u16* __restrict__ B2o,
                                                   const float* __restrict__ bias,
                                                   float* __restrict__ out) {
  __shared__ __align__(16) u16 lds[3][8192];
  const int tid = threadIdx.x;
  const int lane = tid & 63;
  const int l31 = lane & 31, hh = lane >> 5;
  const int wid = tid >> 6;
  const int wmb = (wid >> 1) * 64, wnb = (wid & 1) * 64;
  const int m0 = blockIdx.x * 128;
  const int n0 = blockIdx.y * 128;

  f32x16 acc[2][2] = {};

  auto stage = [&](int buf, int t) {
#pragma unroll
    for (int c = 0; c < 2; ++c) {
      int u = c * 256 + tid;
      int kb = u >> 7, ml = u & 127;
      gload_lds16(A2 + ((size_t)(t * 4 + kb) * MROWS + m0 + ml) * 8,
                  &lds[buf][u * 8]);
    }
#pragma unroll
    for (int c = 0; c < 2; ++c) {
      int u = c * 256 + tid;
      int kb = u >> 7, nl = u & 127;
      gload_lds16(B2o + ((size_t)(t * 4 + kb) * 512 + n0 + nl) * 8,
                  &lds[buf][4096 + u * 8]);
    }
  };

  stage(0, 0);
  stage(1, 1);
#pragma unroll
  for (int t = 0; t < 16; ++t) {
    const int cur = t % 3;
    if (t + 2 < 16) {
      stage((t + 2) % 3, t + 2);
      asm volatile("s_waitcnt vmcnt(8)" ::: "memory");
    } else if (t + 2 == 16) {
      asm volatile("s_waitcnt vmcnt(4)" ::: "memory");
    } else {
      asm volatile("s_waitcnt vmcnt(0)" ::: "memory");
    }
    __builtin_amdgcn_sched_barrier(0);
    __builtin_amdgcn_s_barrier();
    __builtin_amdgcn_sched_barrier(0);
    const u16* LA = &lds[cur][0];
    const u16* LB = &lds[cur][4096];
#pragma unroll
    for (int ks = 0; ks < 2; ++ks) {
      int kb2 = ks * 2 + hh;
      bf16x8 a0 = *reinterpret_cast<const bf16x8*>(LA + (kb2 * 128 + wmb + l31) * 8);
      bf16x8 a1 = *reinterpret_cast<const bf16x8*>(LA + (kb2 * 128 + wmb + 32 + l31) * 8);
      bf16x8 b0 = *reinterpret_cast<const bf16x8*>(LB + (kb2 * 128 + wnb + l31) * 8);
      bf16x8 b1 = *reinterpret_cast<const bf16x8*>(LB + (kb2 * 128 + wnb + 32 + l31) * 8);
      acc[0][0] = __builtin_amdgcn_mfma_f32_32x32x16_bf16(a0, b0, acc[0][0], 0, 0, 0);
      acc[0][1] = __builtin_amdgcn_mfma_f32_32x32x16_bf16(a0, b1, acc[0][1], 0, 0, 0);
      acc[1][0] = __builtin_amdgcn_mfma_f32_32x32x16_bf16(a1, b0, acc[1][0], 0, 0, 0);
      acc[1][1] = __builtin_amdgcn_mfma_f32_32x32x16_bf16(a1, b1, acc[1][1], 0, 0, 0);
    }
    __builtin_amdgcn_sched_barrier(0);
    __builtin_amdgcn_s_barrier();
    __builtin_amdgcn_sched_barrier(0);
  }

#pragma unroll
  for (int nr = 0; nr < 2; ++nr) {
    int col = n0 + wnb + nr * 32 + l31;
    float bv = bias[col];
#pragma unroll
    for (int mr = 0; mr < 2; ++mr)
#pragma unroll
      for (int r = 0; r < 16; ++r) {
        int row = m0 + wmb + mr * 32 + (r & 3) + 8 * (r >> 2) + 4 * hh;
        out[(size_t)row * CDIM + col] = acc[mr][nr][r] + bv;
      }
  }
}

// ---------------- launcher ----------------
extern "C" void kernel_launch(void* const* d_in, const int* in_sizes, int n_in,
                              void* d_out, int out_size, void* d_ws, size_t ws_size,
                              hipStream_t stream) {
  const float* x  = (const float*)d_in[0];
  const float* Wq = (const float*)d_in[1];
  const float* Wk = (const float*)d_in[2];
  const float* Wv = (const float*)d_in[3];
  const float* Wo = (const float*)d_in[4];
  const float* bo = (const float*)d_in[5];
  float* out = (float*)d_out;

  char* p = (char*)d_ws;
  const size_t big = (size_t)MROWS * CDIM * 2;     // 16.78 MB
  u16* A2x  = (u16*)p; p += big;   // x k-blocked; attn overwrites with O k-blocked
  u16* B2   = (u16*)p; p += (size_t)3 * 64 * 512 * 8 * 2;
  u16* B2o  = (u16*)p; p += (size_t)64 * 512 * 8 * 2;
  float* cosT = (float*)p; p += (size_t)TSEQ * 32 * 4;
  float* sinT = (float*)p; p += (size_t)TSEQ * 32 * 4;
  u16* Qb   = (u16*)p; p += big;
  u16* Kf   = (u16*)p; p += big;   // fragment-packed K (qkv epilogue)
  u16* Vf   = (u16*)p; p += big;   // fragment-packed V (qkv epilogue)

  hipLaunchKernelGGL(conv_x, dim3(MROWS / 128, 4), dim3(256), 0, stream, x, A2x);
  hipLaunchKernelGGL(transpose_w, dim3(8, 4, 4), dim3(256), 0, stream,
                     Wq, Wk, Wv, Wo, B2, B2o);
  hipLaunchKernelGGL(rope_tab, dim3(TSEQ * 32 / 256), dim3(256), 0, stream, cosT, sinT);
  hipLaunchKernelGGL(qkv_gemm, dim3(MROWS / 256, 1536 / 256), dim3(512), 0, stream,
                     A2x, B2, cosT, sinT, Qb, Kf, Vf);
  hipLaunchKernelGGL(attn_kern, dim3(BBATCH * NH, TSEQ / 64), dim3(128), 0, stream,
                     Qb, Kf, Vf, A2x);
  hipLaunchKernelGGL(out_gemm, dim3(MROWS / 128, CDIM / 128), dim3(256), 0, stream,
                     A2x, B2o, bo, out);
}

// Round 23
// 91.304 us; speedup vs baseline: 1.2513x; 1.2513x over previous
//
#include <hip/hip_runtime.h>

#define TSEQ 512
#define CDIM 512
#define NH 8
#define HS 64
#define BBATCH 32
#define MROWS (BBATCH * TSEQ)   // 16384

typedef unsigned short u16;
typedef __bf16 bf16x8 __attribute__((ext_vector_type(8)));
typedef float f32x4 __attribute__((ext_vector_type(4)));
typedef float f32x16 __attribute__((ext_vector_type(16)));

// round-to-nearest-even fp32 -> bf16 bits
__device__ __forceinline__ u16 f2b(float f) {
  union { float f; unsigned u; } v; v.f = f;
  unsigned r = (v.u + 0x7fffu + ((v.u >> 16) & 1u)) >> 16;
  return (u16)r;
}

__device__ __forceinline__ void gload_lds16(const u16* g, u16* l) {
  __builtin_amdgcn_global_load_lds(
      (const __attribute__((address_space(1))) void*)g,
      (__attribute__((address_space(3))) void*)l, 16, 0, 0);
}

// ---------------- prep kernels ----------------
// k-blocked layout: 16B "units"; unit (kb, dim)[j] = M[kb*8+j][dim].

// x fp32 [16384][512] -> A2 units [64 kb][16384 m].  grid (128, 4)
__global__ __launch_bounds__(256) void conv_x(const float* __restrict__ x,
                                              u16* __restrict__ A2) {
  __shared__ __align__(16) u16 tile[128][136];
  const int tid = threadIdx.x;
  const int m0 = blockIdx.x * 128;
  const int cc = blockIdx.y;
#pragma unroll
  for (int i = 0; i < 16; ++i) {
    int idx = i * 256 + tid;
    int ml = idx >> 5, c4 = idx & 31;
    float4 v = *reinterpret_cast<const float4*>(
        x + (size_t)(m0 + ml) * CDIM + cc * 128 + c4 * 4);
    ushort4 o; o.x = f2b(v.x); o.y = f2b(v.y); o.z = f2b(v.z); o.w = f2b(v.w);
    *reinterpret_cast<ushort4*>(&tile[ml][c4 * 4]) = o;
  }
  __syncthreads();
#pragma unroll
  for (int i = 0; i < 8; ++i) {
    int uid = i * 256 + tid;
    int kb = uid >> 7, ml = uid & 127;
    int4 v = *reinterpret_cast<const int4*>(&tile[ml][kb * 8]);
    *reinterpret_cast<int4*>(A2 + ((size_t)(cc * 16 + kb) * MROWS + m0 + ml) * 8) = v;
  }
}

// W fp32 [512 K][512 N] (natural) -> B2 units [64 kb][512 n] per matrix
__global__ __launch_bounds__(256) void transpose_w(const float* __restrict__ wq,
                                                   const float* __restrict__ wk,
                                                   const float* __restrict__ wv,
                                                   const float* __restrict__ wo,
                                                   u16* __restrict__ B2,
                                                   u16* __restrict__ B2o) {
  __shared__ __align__(16) u16 tile[64][136];
  const int tid = threadIdx.x;
  int mat = blockIdx.z;
  const float* src = (mat == 0) ? wq : (mat == 1) ? wk : (mat == 2) ? wv : wo;
  u16* dst = (mat < 3) ? (B2 + (size_t)mat * 64 * 512 * 8) : B2o;
  const int k0 = blockIdx.x * 64, n0 = blockIdx.y * 128;
#pragma unroll
  for (int i = 0; i < 8; ++i) {
    int idx = i * 256 + tid;
    int kl = idx >> 5, c4 = idx & 31;
    float4 v = *reinterpret_cast<const float4*>(
        src + (size_t)(k0 + kl) * CDIM + n0 + c4 * 4);
    ushort4 o; o.x = f2b(v.x); o.y = f2b(v.y); o.z = f2b(v.z); o.w = f2b(v.w);
    *reinterpret_cast<ushort4*>(&tile[kl][c4 * 4]) = o;
  }
  __syncthreads();
#pragma unroll
  for (int i = 0; i < 4; ++i) {
    int uid = i * 256 + tid;
    int kb = uid >> 7, nl = uid & 127;
    ushort4 lo, hi;
    lo.x = tile[kb * 8 + 0][nl]; lo.y = tile[kb * 8 + 1][nl];
    lo.z = tile[kb * 8 + 2][nl]; lo.w = tile[kb * 8 + 3][nl];
    hi.x = tile[kb * 8 + 4][nl]; hi.y = tile[kb * 8 + 5][nl];
    hi.z = tile[kb * 8 + 6][nl]; hi.w = tile[kb * 8 + 7][nl];
    u16* d = dst + ((size_t)(k0 / 8 + kb) * 512 + n0 + nl) * 8;
    *reinterpret_cast<ushort4*>(d) = lo;
    *reinterpret_cast<ushort4*>(d + 4) = hi;
  }
}

__global__ __launch_bounds__(256) void rope_tab(float* __restrict__ cosT,
                                                float* __restrict__ sinT) {
  int i = blockIdx.x * 256 + threadIdx.x;       // 512*32
  int t = i >> 5, f = i & 31;
  float inv = __powf(10000.0f, -(float)f / 32.0f);
  float ang = (float)t * inv;
  cosT[i] = cosf(ang);
  sinT[i] = sinf(ang);
}

// ------ fused QKV GEMM + RoPE (BK=32, 3-buf counted vmcnt) -----------------
// Epilogue: Q natural (pre-scaled); K AND V stored fragment-packed for attn.
__global__ __launch_bounds__(256, 2) void qkv_gemm(const u16* __restrict__ A2,
                                                   const u16* __restrict__ B2,
                                                   const float* __restrict__ cosT,
                                                   const float* __restrict__ sinT,
                                                   u16* __restrict__ Qb,
                                                   u16* __restrict__ Kf,
                                                   u16* __restrict__ Vf) {
  __shared__ __align__(16) u16 lds[3][8192];    // 48 KB
  const int tid = threadIdx.x;
  const int lane = tid & 63;
  const int l31 = lane & 31, hh = lane >> 5;
  const int wid = tid >> 6;
  const int wmb = (wid >> 1) * 64, wnb = (wid & 1) * 64;
  const int m0 = blockIdx.x * 128;
  const int n0 = blockIdx.y * 128;
  const int mat = n0 >> 9;                       // 0:Q 1:K 2:V (no straddle)
  const int nc0 = n0 & 511;
  const u16* B2m = B2 + (size_t)mat * (64 * 512 * 8);

  f32x16 acc[2][2] = {};

  auto stage = [&](int buf, int t) {             // 4 gload_lds per wave
#pragma unroll
    for (int c = 0; c < 2; ++c) {
      int u = c * 256 + tid;
      int kb = u >> 7, ml = u & 127;
      gload_lds16(A2 + ((size_t)(t * 4 + kb) * MROWS + m0 + ml) * 8,
                  &lds[buf][u * 8]);
    }
#pragma unroll
    for (int c = 0; c < 2; ++c) {
      int u = c * 256 + tid;
      int kb = u >> 7, nl = u & 127;
      gload_lds16(B2m + ((size_t)(t * 4 + kb) * 512 + nc0 + nl) * 8,
                  &lds[buf][4096 + u * 8]);
    }
  };

  stage(0, 0);
  stage(1, 1);
#pragma unroll
  for (int t = 0; t < 16; ++t) {
    const int cur = t % 3;
    if (t + 2 < 16) {
      stage((t + 2) % 3, t + 2);
      asm volatile("s_waitcnt vmcnt(8)" ::: "memory");   // stage(t) done
    } else if (t + 2 == 16) {
      asm volatile("s_waitcnt vmcnt(4)" ::: "memory");
    } else {
      asm volatile("s_waitcnt vmcnt(0)" ::: "memory");
    }
    __builtin_amdgcn_sched_barrier(0);
    __builtin_amdgcn_s_barrier();
    __builtin_amdgcn_sched_barrier(0);
    const u16* LA = &lds[cur][0];
    const u16* LB = &lds[cur][4096];
#pragma unroll
    for (int ks = 0; ks < 2; ++ks) {
      int kb2 = ks * 2 + hh;
      bf16x8 a0 = *reinterpret_cast<const bf16x8*>(LA + (kb2 * 128 + wmb + l31) * 8);
      bf16x8 a1 = *reinterpret_cast<const bf16x8*>(LA + (kb2 * 128 + wmb + 32 + l31) * 8);
      bf16x8 b0 = *reinterpret_cast<const bf16x8*>(LB + (kb2 * 128 + wnb + l31) * 8);
      bf16x8 b1 = *reinterpret_cast<const bf16x8*>(LB + (kb2 * 128 + wnb + 32 + l31) * 8);
      acc[0][0] = __builtin_amdgcn_mfma_f32_32x32x16_bf16(a0, b0, acc[0][0], 0, 0, 0);
      acc[0][1] = __builtin_amdgcn_mfma_f32_32x32x16_bf16(a0, b1, acc[0][1], 0, 0, 0);
      acc[1][0] = __builtin_amdgcn_mfma_f32_32x32x16_bf16(a1, b0, acc[1][0], 0, 0, 0);
      acc[1][1] = __builtin_amdgcn_mfma_f32_32x32x16_bf16(a1, b1, acc[1][1], 0, 0, 0);
    }
    __builtin_amdgcn_sched_barrier(0);
    __builtin_amdgcn_s_barrier();
    __builtin_amdgcn_sched_barrier(0);
  }

  const int bidx = m0 >> 9;
  if (mat == 0) {
    // Q: RoPE + pre-scale, natural layout
    const float qs = 0.125f * 1.4426950408889634f;
#pragma unroll
    for (int nr = 0; nr < 2; ++nr) {
      int nc = nc0 + wnb + nr * 32 + l31;
      int fi = (nc & 63) >> 1;
      int odd = nc & 1;
#pragma unroll
      for (int mr = 0; mr < 2; ++mr)
#pragma unroll
        for (int r = 0; r < 16; ++r) {
          int row = m0 + wmb + mr * 32 + (r & 3) + 8 * (r >> 2) + 4 * hh;
          int tq = row & (TSEQ - 1);
          float v = acc[mr][nr][r];
          float o = __shfl_xor(v, 1);
          float c = cosT[tq * 32 + fi], sn = sinT[tq * 32 + fi];
          float res = odd ? (v * c + o * sn) : (v * c - o * sn);
          Qb[(size_t)row * CDIM + nc] = f2b(res * qs);
        }
    }
  } else if (mat == 1) {
    // K: RoPE then fragment-packed store. K[t][h*64+e] ->
    // Kf[(((b*8+h)*16 + t>>5)*64 + ((e>>3)&1)*32 + (t&31))*32 + (e>>4)*8 + (e&7)]
#pragma unroll
    for (int nr = 0; nr < 2; ++nr) {
      int nc = nc0 + wnb + nr * 32 + l31;
      int h2 = nc >> 6, e = nc & 63;
      int fi = e >> 1;
      int odd = nc & 1;
      int laneHi = ((e >> 3) & 1) * 32;
      int idx = ((e >> 4) * 8) + (e & 7);
#pragma unroll
      for (int mr = 0; mr < 2; ++mr)
#pragma unroll
        for (int r = 0; r < 16; ++r) {
          int row = m0 + wmb + mr * 32 + (r & 3) + 8 * (r >> 2) + 4 * hh;
          int tq = row & (TSEQ - 1);
          float v = acc[mr][nr][r];
          float o = __shfl_xor(v, 1);
          float c = cosT[tq * 32 + fi], sn = sinT[tq * 32 + fi];
          float res = odd ? (v * c + o * sn) : (v * c - o * sn);
          size_t addr = ((((size_t)(bidx * 8 + h2) * 16 + (tq >> 5)) * 64)
                         + laneHi + (tq & 31)) * 32 + idx;
          Kf[addr] = f2b(res);
        }
    }
  } else {
    // V: fragment-packed store (inverse of the verified vt_t/attn pair):
    // V[t][h*64+e] -> Vf[(((b*8+h)*16 + t>>5)*64 + ((t>>3)&1)*32 + (e&31))*32
    //                   + ((e>>5)*2 + ((t>>4)&1))*8 + (t&7)]
#pragma unroll
    for (int nr = 0; nr < 2; ++nr) {
      int nc = nc0 + wnb + nr * 32 + l31;
      int h2 = nc >> 6, e = nc & 63;
      int e31 = e & 31, eHi = e >> 5;
#pragma unroll
      for (int mr = 0; mr < 2; ++mr)
#pragma unroll
        for (int r = 0; r < 16; ++r) {
          int row = m0 + wmb + mr * 32 + (r & 3) + 8 * (r >> 2) + 4 * hh;
          int tq = row & (TSEQ - 1);
          int t5 = tq & 31;
          size_t addr = ((((size_t)(bidx * 8 + h2) * 16 + (tq >> 5)) * 64)
                         + ((t5 >> 3) & 1) * 32 + e31) * 32
                        + (eHi * 2 + ((t5 >> 4) & 1)) * 8 + (t5 & 7);
          Vf[addr] = f2b(acc[mr][nr][r]);
        }
    }
  }
}

// -------- flash attention (frag-packed K/V + fixed-base softmax) ----------
__global__ __launch_bounds__(128, 4) void attn_kern(const u16* __restrict__ Qb,
                                                    const u16* __restrict__ Kf,
                                                    const u16* __restrict__ Vf,
                                                    u16* __restrict__ A2out) {
  const int lane = threadIdx.x & 63, wid = threadIdx.x >> 6;
  const int l31 = lane & 31, hh = lane >> 5;
  const int bh = blockIdx.x, b = bh >> 3, h = bh & 7;
  const int q0 = blockIdx.y * 64 + wid * 32;

  bf16x8 qf[4];
  const u16* qbase = Qb + (size_t)(b * TSEQ + q0 + l31) * CDIM + h * HS + hh * 8;
#pragma unroll
  for (int ds = 0; ds < 4; ++ds)
    qf[ds] = *reinterpret_cast<const bf16x8*>(qbase + ds * 16);

  float lsum = 0.0f;
  f32x16 of[2] = {};

  const int nkt = (q0 >> 5) + 1;
  for (int kt = 0; kt < nkt; ++kt) {
    const u16* kfr = Kf + (((size_t)bh * 16 + kt) * 64 + lane) * 32;
    f32x16 s = {};
    __builtin_amdgcn_s_setprio(1);
#pragma unroll
    for (int ds = 0; ds < 4; ++ds) {
      bf16x8 kf = *reinterpret_cast<const bf16x8*>(kfr + ds * 8);
      s = __builtin_amdgcn_mfma_f32_32x32x16_bf16(kf, qf[ds], s, 0, 0, 0);
    }
    __builtin_amdgcn_s_setprio(0);
    float p[16];
    if (kt == nkt - 1) {          // diagonal tile: zero k > q after exp
#pragma unroll
      for (int r = 0; r < 16; ++r) {
        int kk = (r & 3) + 8 * (r >> 2) + 4 * hh;
        p[r] = (kk > l31) ? 0.0f : exp2f(s[r]);
      }
    } else {
#pragma unroll
      for (int r = 0; r < 16; ++r) p[r] = exp2f(s[r]);
    }
    float ts = 0.0f;
#pragma unroll
    for (int r = 0; r < 16; ++r) ts += p[r];
    ts += __shfl_xor(ts, 32);
    lsum += ts;

    unsigned w0, w1, w2, w3, w4, w5, w6, w7;
    asm("v_cvt_pk_bf16_f32 %0, %1, %2" : "=v"(w0) : "v"(p[0]),  "v"(p[1]));
    asm("v_cvt_pk_bf16_f32 %0, %1, %2" : "=v"(w1) : "v"(p[2]),  "v"(p[3]));
    asm("v_cvt_pk_bf16_f32 %0, %1, %2" : "=v"(w2) : "v"(p[4]),  "v"(p[5]));
    asm("v_cvt_pk_bf16_f32 %0, %1, %2" : "=v"(w3) : "v"(p[6]),  "v"(p[7]));
    asm("v_cvt_pk_bf16_f32 %0, %1, %2" : "=v"(w4) : "v"(p[8]),  "v"(p[9]));
    asm("v_cvt_pk_bf16_f32 %0, %1, %2" : "=v"(w5) : "v"(p[10]), "v"(p[11]));
    asm("v_cvt_pk_bf16_f32 %0, %1, %2" : "=v"(w6) : "v"(p[12]), "v"(p[13]));
    asm("v_cvt_pk_bf16_f32 %0, %1, %2" : "=v"(w7) : "v"(p[14]), "v"(p[15]));
    asm("v_permlane32_swap_b32 %0, %1" : "+v"(w0), "+v"(w2));
    asm("v_permlane32_swap_b32 %0, %1" : "+v"(w1), "+v"(w3));
    asm("v_permlane32_swap_b32 %0, %1" : "+v"(w4), "+v"(w6));
    asm("v_permlane32_swap_b32 %0, %1" : "+v"(w5), "+v"(w7));
    union { unsigned u[4]; bf16x8 v; } pb0, pb1;
    pb0.u[0] = w0; pb0.u[1] = w1; pb0.u[2] = w2; pb0.u[3] = w3;
    pb1.u[0] = w4; pb1.u[1] = w5; pb1.u[2] = w6; pb1.u[3] = w7;

    const u16* vfr = Vf + (((size_t)bh * 16 + kt) * 64 + lane) * 32;
    bf16x8 vf00 = *reinterpret_cast<const bf16x8*>(vfr);
    bf16x8 vf01 = *reinterpret_cast<const bf16x8*>(vfr + 8);
    bf16x8 vf10 = *reinterpret_cast<const bf16x8*>(vfr + 16);
    bf16x8 vf11 = *reinterpret_cast<const bf16x8*>(vfr + 24);
    __builtin_amdgcn_s_setprio(1);
    of[0] = __builtin_amdgcn_mfma_f32_32x32x16_bf16(vf00, pb0.v, of[0], 0, 0, 0);
    of[0] = __builtin_amdgcn_mfma_f32_32x32x16_bf16(vf01, pb1.v, of[0], 0, 0, 0);
    of[1] = __builtin_amdgcn_mfma_f32_32x32x16_bf16(vf10, pb0.v, of[1], 0, 0, 0);
    of[1] = __builtin_amdgcn_mfma_f32_32x32x16_bf16(vf11, pb1.v, of[1], 0, 0, 0);
    __builtin_amdgcn_s_setprio(0);
  }

  // ---- write O directly in k-blocked A2 units ----
  float inv = 1.0f / lsum;
  const int grow = b * TSEQ + q0 + l31;
#pragma unroll
  for (int dt = 0; dt < 2; ++dt)
#pragma unroll
    for (int i = 0; i < 8; ++i) {
      ushort2 st;
      st.x = f2b(of[dt][2 * i] * inv);
      st.y = f2b(of[dt][2 * i + 1] * inv);
      int kb = h * 8 + dt * 4 + ((2 * i) >> 2);
      int off = ((2 * i) & 3) + 4 * hh;
      *reinterpret_cast<ushort2*>(
          A2out + ((size_t)kb * MROWS + grow) * 8 + off) = st;
    }
}

// ------- output projection (32x32 MFMA, BK=32, 3-buf counted vmcnt) --------
__global__ __launch_bounds__(256, 2) void out_gemm(const u16* __restrict__ A2,
                                                   const u16* __restrict__ B2o,
                                                   const float* __restrict__ bias,
                                                   float* __restrict__ out) {
  __shared__ __align__(16) u16 lds[3][8192];
  const int tid = threadIdx.x;
  const int lane = tid & 63;
  const int l31 = lane & 31, hh = lane >> 5;
  const int wid = tid >> 6;
  const int wmb = (wid >> 1) * 64, wnb = (wid & 1) * 64;
  const int m0 = blockIdx.x * 128;
  const int n0 = blockIdx.y * 128;

  f32x16 acc[2][2] = {};

  auto stage = [&](int buf, int t) {
#pragma unroll
    for (int c = 0; c < 2; ++c) {
      int u = c * 256 + tid;
      int kb = u >> 7, ml = u & 127;
      gload_lds16(A2 + ((size_t)(t * 4 + kb) * MROWS + m0 + ml) * 8,
                  &lds[buf][u * 8]);
    }
#pragma unroll
    for (int c = 0; c < 2; ++c) {
      int u = c * 256 + tid;
      int kb = u >> 7, nl = u & 127;
      gload_lds16(B2o + ((size_t)(t * 4 + kb) * 512 + n0 + nl) * 8,
                  &lds[buf][4096 + u * 8]);
    }
  };

  stage(0, 0);
  stage(1, 1);
#pragma unroll
  for (int t = 0; t < 16; ++t) {
    const int cur = t % 3;
    if (t + 2 < 16) {
      stage((t + 2) % 3, t + 2);
      asm volatile("s_waitcnt vmcnt(8)" ::: "memory");
    } else if (t + 2 == 16) {
      asm volatile("s_waitcnt vmcnt(4)" ::: "memory");
    } else {
      asm volatile("s_waitcnt vmcnt(0)" ::: "memory");
    }
    __builtin_amdgcn_sched_barrier(0);
    __builtin_amdgcn_s_barrier();
    __builtin_amdgcn_sched_barrier(0);
    const u16* LA = &lds[cur][0];
    const u16* LB = &lds[cur][4096];
#pragma unroll
    for (int ks = 0; ks < 2; ++ks) {
      int kb2 = ks * 2 + hh;
      bf16x8 a0 = *reinterpret_cast<const bf16x8*>(LA + (kb2 * 128 + wmb + l31) * 8);
      bf16x8 a1 = *reinterpret_cast<const bf16x8*>(LA + (kb2 * 128 + wmb + 32 + l31) * 8);
      bf16x8 b0 = *reinterpret_cast<const bf16x8*>(LB + (kb2 * 128 + wnb + l31) * 8);
      bf16x8 b1 = *reinterpret_cast<const bf16x8*>(LB + (kb2 * 128 + wnb + 32 + l31) * 8);
      acc[0][0] = __builtin_amdgcn_mfma_f32_32x32x16_bf16(a0, b0, acc[0][0], 0, 0, 0);
      acc[0][1] = __builtin_amdgcn_mfma_f32_32x32x16_bf16(a0, b1, acc[0][1], 0, 0, 0);
      acc[1][0] = __builtin_amdgcn_mfma_f32_32x32x16_bf16(a1, b0, acc[1][0], 0, 0, 0);
      acc[1][1] = __builtin_amdgcn_mfma_f32_32x32x16_bf16(a1, b1, acc[1][1], 0, 0, 0);
    }
    __builtin_amdgcn_sched_barrier(0);
    __builtin_amdgcn_s_barrier();
    __builtin_amdgcn_sched_barrier(0);
  }

#pragma unroll
  for (int nr = 0; nr < 2; ++nr) {
    int col = n0 + wnb + nr * 32 + l31;
    float bv = bias[col];
#pragma unroll
    for (int mr = 0; mr < 2; ++mr)
#pragma unroll
      for (int r = 0; r < 16; ++r) {
        int row = m0 + wmb + mr * 32 + (r & 3) + 8 * (r >> 2) + 4 * hh;
        out[(size_t)row * CDIM + col] = acc[mr][nr][r] + bv;
      }
  }
}

// ---------------- launcher ----------------
extern "C" void kernel_launch(void* const* d_in, const int* in_sizes, int n_in,
                              void* d_out, int out_size, void* d_ws, size_t ws_size,
                              hipStream_t stream) {
  const float* x  = (const float*)d_in[0];
  const float* Wq = (const float*)d_in[1];
  const float* Wk = (const float*)d_in[2];
  const float* Wv = (const float*)d_in[3];
  const float* Wo = (const float*)d_in[4];
  const float* bo = (const float*)d_in[5];
  float* out = (float*)d_out;

  char* p = (char*)d_ws;
  const size_t big = (size_t)MROWS * CDIM * 2;     // 16.78 MB
  u16* A2x  = (u16*)p; p += big;   // x k-blocked; attn overwrites with O k-blocked
  u16* B2   = (u16*)p; p += (size_t)3 * 64 * 512 * 8 * 2;
  u16* B2o  = (u16*)p; p += (size_t)64 * 512 * 8 * 2;
  float* cosT = (float*)p; p += (size_t)TSEQ * 32 * 4;
  float* sinT = (float*)p; p += (size_t)TSEQ * 32 * 4;
  u16* Qb   = (u16*)p; p += big;
  u16* Kf   = (u16*)p; p += big;   // fragment-packed K (qkv epilogue)
  u16* Vf   = (u16*)p; p += big;   // fragment-packed V (qkv epilogue)

  hipLaunchKernelGGL(conv_x, dim3(MROWS / 128, 4), dim3(256), 0, stream, x, A2x);
  hipLaunchKernelGGL(transpose_w, dim3(8, 4, 4), dim3(256), 0, stream,
                     Wq, Wk, Wv, Wo, B2, B2o);
  hipLaunchKernelGGL(rope_tab, dim3(TSEQ * 32 / 256), dim3(256), 0, stream, cosT, sinT);
  hipLaunchKernelGGL(qkv_gemm, dim3(MROWS / 128, 1536 / 128), dim3(256), 0, stream,
                     A2x, B2, cosT, sinT, Qb, Kf, Vf);
  hipLaunchKernelGGL(attn_kern, dim3(BBATCH * NH, TSEQ / 64), dim3(128), 0, stream,
                     Qb, Kf, Vf, A2x);
  hipLaunchKernelGGL(out_gemm, dim3(MROWS / 128, CDIM / 128), dim3(256), 0, stream,
                     A2x, B2o, bo, out);
}